// Round 8
// baseline (253.745 us; speedup 1.0000x reference)
//
#include <hip/hip_runtime.h>
#include <hip/hip_bf16.h>
#include <math.h>

// ---- problem constants ----
constexpr int BB    = 1024;
constexpr int NN    = 50;
constexpr int RR    = 1000;
constexpr int DD    = 128;
constexpr int NPOIS = 50000;
#define DEG2RADF  0.017453292519943295f
#define KHALF     0.008726646259971648f   // DEG2RAD/2
#define RSQRTD    0.08838834764831845f    // 1/sqrt(128)
#define LOG2E     1.4426950408889634f
#define LN2       0.6931471805599453f
#define DBIN_C0   4013.7373f
#define DBIN_C1   668.95621f
#define TBIN_SC   0.00625f                // 63/10080
#define PENAL     -1.0e30f                // additive mask sentinel

typedef __attribute__((ext_vector_type(8))) short bfrag8;
typedef __attribute__((ext_vector_type(4))) float f32x4;

// XOR-swizzled LDS tile addressing (shorts). Row stride 128 shorts;
// 16-B block j of row r lives at physical block j ^ (r & 7).
// All MFMA fragment-row indices are ≡ colr (mod 8), so for a fragment read of
// logical k-chunk ks the physical offset is  base + kx + ks*32  (even ks) or
// base - kx + ks*32  (odd ks), with base = colr*128 + 8*(quad^(colr&3)) and
// kx = 32*((colr>>2)&1).  Iterate LOGICAL ks: bit 2 of the physical block
// index then varies ACROSS LANES per instruction (all 32 banks covered,
// 8 lanes/bank = conflict-free minimum).  (Round 1 measured: physical-index
// iteration doubles SQ_LDS_BANK_CONFLICT.)
__device__ __forceinline__ int swz128(int row, int k) {
    return row * 128 + ((((k) >> 3) ^ (row & 7)) << 3) + (k & 7);
}

__device__ __forceinline__ unsigned short f2bf(float x) {
    union { __hip_bfloat16 h; unsigned short u; } cv;
    cv.h = __float2bfloat16(x);
    return cv.u;
}

__device__ __forceinline__ float exp2_asm(float x) {   // v_exp_f32: D = 2^S0
    float r;
    asm("v_exp_f32 %0, %1" : "=v"(r) : "v"(x));
    return r;
}

__device__ __forceinline__ float fract_asm(float x) {  // D = S0 - floor(S0)
    float r;
    asm("v_fract_f32 %0, %1" : "=v"(r) : "v"(x));
    return r;
}

__device__ __forceinline__ float cos_small(float x) {
    float x2 = x * x;
    return 1.0f - 0.5f * x2 + 0.041666667f * x2 * x2;
}

// ---- precompute (merged): Mt and Gp, both bf16 with LOG2E/sqrt(D) folded ----
// Gp in MFMA B-fragment order: Gp[rt][wid][ks][lane][8], lane = quad*16+colr,
// r = rt*64 + wid*16 + colr, k = ks*32 + quad*8 + k7. Rows 1000..1023 zeroed.
__global__ void prep_mg(const float* __restrict__ Wq, const float* __restrict__ Wk,
                        const float* __restrict__ Wv, const float* __restrict__ Re,
                        unsigned short* __restrict__ Mt, unsigned short* __restrict__ Gp) {
    int k = threadIdx.x;
    if (blockIdx.x < DD) {
        int c = blockIdx.x;
        float s0 = 0.f, s1 = 0.f, s2 = 0.f, s3 = 0.f;
        for (int d = 0; d < DD; d += 4) {
            s0 += Wq[(d + 0) * DD + k] * Wk[(d + 0) * DD + c];
            s1 += Wq[(d + 1) * DD + k] * Wk[(d + 1) * DD + c];
            s2 += Wq[(d + 2) * DD + k] * Wk[(d + 2) * DD + c];
            s3 += Wq[(d + 3) * DD + k] * Wk[(d + 3) * DD + c];
        }
        Mt[c * DD + k] = f2bf((s0 + s1 + s2 + s3) * (RSQRTD * LOG2E));
    } else {
        int r = blockIdx.x - DD;
        float val = 0.f;
        if (r < RR) {
            float s0 = 0.f, s1 = 0.f, s2 = 0.f, s3 = 0.f;
            for (int d = 0; d < DD; d += 4) {
                s0 += Wv[(d + 0) * DD + k] * Re[r * DD + d + 0];
                s1 += Wv[(d + 1) * DD + k] * Re[r * DD + d + 1];
                s2 += Wv[(d + 2) * DD + k] * Re[r * DD + d + 2];
                s3 += Wv[(d + 3) * DD + k] * Re[r * DD + d + 3];
            }
            val = (s0 + s1 + s2 + s3) * (RSQRTD * LOG2E);
        }
        int rt = r >> 6, widr = (r >> 4) & 3, colr = r & 15;
        int ks = k >> 5, quad = (k >> 3) & 3, k7 = k & 7;
        int lane = quad * 16 + colr;
        Gp[((((rt * 16 + widr * 4 + ks) * 64) + lane) << 3) + k7] = f2bf(val);
    }
}

// ---- fused: per-b attention (4 MFMA phases) + match (16 rt-tiles) ----
// Z never touches HBM: accZ registers -> swizzled LDS (reusing the dead
// ys/ps union as As) -> Af registers -> match loop.
__global__ __launch_bounds__(256, 4) void stan_fused(
    const int* __restrict__ poi_idx, const int* __restrict__ hourw,
    const float* __restrict__ lat, const float* __restrict__ lon,
    const float* __restrict__ tmin,
    const float* __restrict__ poi_emb, const float* __restrict__ time_emb,
    const float* __restrict__ Et_g, const float* __restrict__ Ed_g,
    const float* __restrict__ Em_g,
    const unsigned short* __restrict__ Mtb, const unsigned short* __restrict__ Gp,
    const float* __restrict__ cent, float* __restrict__ out) {
    __shared__ short xs[64 * 128];             // x bf16, swizzled, 16 KB
    __shared__ union {
        short ys[64 * 128];                    // Y bf16, swizzled, 16 KB
        short ps[64 * 64];                     // P bf16, swizzled
        short as_[64 * 128];                   // Z bf16, swizzled (match A-tile)
    } u2;
    __shared__ float2 Et2[64], Ed2[64], Em2[64];  // (e, de) * LOG2E
    __shared__ float4 bnfo[64];                // (latk, lonk, cos, t*TBIN_SC)
    __shared__ float4 bnfoM[64];               // (latk, lonk, cos, pen) for match
    __shared__ float  jpen[64];                // 0 valid / -1e30 pad
    __shared__ int2   nidx[64];                // (poi row, hour row) for gather

    const int b = blockIdx.x, tid = threadIdx.x;
    const int wid = tid >> 6, lane = tid & 63;
    const int quad = lane >> 4, colr = lane & 15;

    if (tid < 64) {
        int kk = tid > 62 ? 62 : tid;
        float t0 = Et_g[kk] * LOG2E, t1 = Et_g[kk + 1] * LOG2E;
        float d0 = Ed_g[kk] * LOG2E, d1 = Ed_g[kk + 1] * LOG2E;
        float e0 = Em_g[kk] * LOG2E, e1 = Em_g[kk + 1] * LOG2E;
        Et2[tid] = make_float2(t0, t1 - t0);
        Ed2[tid] = make_float2(d0, d1 - d0);
        Em2[tid] = make_float2(e0, e1 - e0);
        if (tid < NN) {
            int p = poi_idx[b * NN + tid];
            int pd = (p < 0);
            float la = lat[b * NN + tid], lo = lon[b * NN + tid];
            float cs = cos_small(la * DEG2RADF);
            float pen = pd ? PENAL : 0.f;
            nidx[tid] = make_int2(pd ? NPOIS : p, pd ? 0 : hourw[b * NN + tid]);
            bnfo[tid]  = make_float4(la * KHALF, lo * KHALF, cs,
                                     tmin[b * NN + tid] * TBIN_SC);
            bnfoM[tid] = make_float4(la * KHALF, lo * KHALF, cs, pen);
            jpen[tid] = pen;
        } else {
            // poi_emb[NPOIS] and time_emb[0] are all-zero rows -> x row = 0
            nidx[tid] = make_int2(NPOIS, 0);
            bnfo[tid]  = make_float4(0.f, 0.f, 1.f, 0.f);
            bnfoM[tid] = make_float4(0.f, 0.f, 1.f, PENAL);
            jpen[tid] = PENAL;
        }
    }
    __syncthreads();

    // ---- phase 1: gather x -> xs (bf16, swizzled u32 stores) ----
    for (int idx = tid; idx < 64 * 64; idx += 256) {
        int n = idx >> 6, c2 = idx & 63;       // c2 = dword index within row
        int2 ix = nidx[n];
        float2 pe = ((const float2*)(poi_emb  + (size_t)ix.x * DD))[c2];
        float2 te = ((const float2*)(time_emb + (size_t)ix.y * DD))[c2];
        unsigned pack = (unsigned)f2bf(pe.x + te.x)
                      | ((unsigned)f2bf(pe.y + te.y) << 16);
        ((unsigned*)xs)[n * 64 + (((c2 >> 2) ^ (n & 7)) << 2) + (c2 & 3)] = pack;
    }
    __syncthreads();

    // thread-constant swizzle bases (see comment at swz128)
    const int q8    = (quad ^ (colr & 3)) * 8;
    const int kx    = (colr & 4) * 8;          // ((colr>>2)&1)*32
    const int xbase = colr * 128 + q8;
    const int xe = xbase + kx, xo = xbase - kx;

    // xs A-fragments hoisted ONCE (64 VGPR) — used by BOTH phase 2 and 3
    bfrag8 Xf[4][4];                   // [mt][ks]
    #pragma unroll
    for (int ks = 0; ks < 4; ks++) {
        const int xoff = ((ks & 1) ? xo : xe) + ks * 32;
        #pragma unroll
        for (int mt = 0; mt < 4; mt++)
            Xf[mt][ks] = *(const bfrag8*)(&xs[xoff + mt * 2048]);
    }

    // ---- phase 2: Y = x @ Mt^T (MFMA), Mt streamed from L1/L2 ----
    {
        f32x4 accY[2][4];
        #pragma unroll
        for (int ct = 0; ct < 2; ct++)
            #pragma unroll
            for (int mt = 0; mt < 4; mt++) accY[ct][mt] = (f32x4){0.f, 0.f, 0.f, 0.f};
        #pragma unroll
        for (int ks = 0; ks < 4; ks++) {
            const int k0 = ks * 32 + quad * 8;                 // logical (global Mt read)
            bfrag8 bv[2];
            #pragma unroll
            for (int ct = 0; ct < 2; ct++) {
                int c = wid * 32 + ct * 16 + colr;
                bv[ct] = *(const bfrag8*)(Mtb + (size_t)c * DD + k0);
            }
            #pragma unroll
            for (int ct = 0; ct < 2; ct++)
                #pragma unroll
                for (int mt = 0; mt < 4; mt++)
                    accY[ct][mt] = __builtin_amdgcn_mfma_f32_16x16x32_bf16(
                        Xf[mt][ks], bv[ct], accY[ct][mt], 0, 0, 0);
        }
        #pragma unroll
        for (int ct = 0; ct < 2; ct++)
            #pragma unroll
            for (int mt = 0; mt < 4; mt++)
                #pragma unroll
                for (int reg = 0; reg < 4; reg++) {
                    int m = mt * 16 + quad * 4 + reg;
                    int c = wid * 32 + ct * 16 + colr;
                    u2.ys[swz128(m, c)] = (short)f2bf(accY[ct][mt][reg]);
                }
    }
    __syncthreads();

    // ---- phase 3: S^T = x @ Y^T (MFMA). C: row=j, col=i=wid*16+colr ----
    const int i = wid * 16 + colr;
    const int ybase = xbase + wid * 2048;
    const int ye = ybase + kx, yo = ybase - kx;
    f32x4 accS[4];
    #pragma unroll
    for (int mt = 0; mt < 4; mt++) accS[mt] = (f32x4){0.f, 0.f, 0.f, 0.f};
    #pragma unroll
    for (int ks = 0; ks < 4; ks++) {           // LOGICAL order: conflict-free
        const int yoff = ((ks & 1) ? yo : ye) + ks * 32;
        bfrag8 bv = *(const bfrag8*)(&u2.ys[yoff]);
        #pragma unroll
        for (int mt = 0; mt < 4; mt++)
            accS[mt] = __builtin_amdgcn_mfma_f32_16x16x32_bf16(
                Xf[mt][ks], bv, accS[mt], 0, 0, 0);
    }
    __syncthreads();   // ys MFMA reads done; ps may overwrite the union

    // ---- bias + softmax over j (exp2 domain; NO max pass: scores are O(1),
    // pads give exp2(-1e30)=0 exactly; f32 exp2 safe to |s|~120) ----
    {
        const float4 bi = bnfo[i];
        float sv[14];
        #pragma unroll
        for (int mt = 0; mt < 4; mt++) {
            const int nregs = (mt == 3) ? 2 : 4;
            #pragma unroll
            for (int reg = 0; reg < nregs; reg++) {
                int j = mt * 16 + quad * 4 + reg;
                float4 bj = bnfo[j];
                float tb = fabsf(bi.w - bj.w);
                int   kt = (int)tb;
                float ft = fract_asm(tb);
                float2 et = Et2[kt];
                float bt = fmaf(ft, et.y, et.x);
                float du = bi.x - bj.x, dv = bi.y - bj.y;
                float a = fmaf((bi.z * bj.z) * dv, dv, du * du);
                float x = __builtin_amdgcn_sqrtf(a);
                float db = x * fmaf(a, DBIN_C1, DBIN_C0);
                int   kd = (int)db;
                float fd = fract_asm(db);
                float2 ed = Ed2[kd];
                float bd = fmaf(fd, ed.y, ed.x);
                sv[mt * 4 + reg] = (accS[mt][reg] + bt) + (bd + jpen[j]);
            }
        }
        float l = 0.f;
        #pragma unroll
        for (int t = 0; t < 14; t++) {
            float p = exp2_asm(sv[t]);
            sv[t] = p;
            l += p;
        }
        l += __shfl_xor(l, 16, 64);
        l += __shfl_xor(l, 32, 64);
        float rl = __builtin_amdgcn_rcpf(l);
        #pragma unroll
        for (int mt = 0; mt < 4; mt++)
            #pragma unroll
            for (int rp = 0; rp < 2; rp++) {
                int j0 = mt * 16 + quad * 4 + rp * 2;
                unsigned pack;
                if (mt == 3 && rp == 1) {
                    pack = 0u;                 // always-invalid slots: P = 0
                } else {
                    unsigned lo = f2bf(sv[mt * 4 + rp * 2]     * rl);
                    unsigned hi = f2bf(sv[mt * 4 + rp * 2 + 1] * rl);
                    pack = lo | (hi << 16);
                }
                ((unsigned*)u2.ps)[i * 32 + (((j0 >> 3) ^ (i & 7)) << 2) + ((j0 & 7) >> 1)]
                    = pack;
            }
    }
    __syncthreads();

    // ---- phase 4: Z = P @ x (K=64 over j); then accZ -> As (swizzled LDS) ----
    {
        f32x4 accZ[2][4];
        #pragma unroll
        for (int nt = 0; nt < 2; nt++)
            #pragma unroll
            for (int mt = 0; mt < 4; mt++) accZ[nt][mt] = (f32x4){0.f, 0.f, 0.f, 0.f};
        union BF { unsigned u[4]; bfrag8 v; };
        const int pbase = colr * 64 + q8;
        const int pe = pbase + kx, po = pbase - kx;
        #pragma unroll
        for (int ks = 0; ks < 2; ks++) {
            const int k0 = ks * 32 + quad * 8;                 // logical (xs gather)
            const int poff = ((ks & 1) ? po : pe) + ks * 32;   // physical (ps reads)
            bfrag8 av[4];
            #pragma unroll
            for (int mt = 0; mt < 4; mt++)
                av[mt] = *(const bfrag8*)(&u2.ps[poff + mt * 1024]);
            BF bvx[2];
            #pragma unroll
            for (int nt = 0; nt < 2; nt++) {
                int d = wid * 32 + nt * 16 + colr;
                #pragma unroll
                for (int t2 = 0; t2 < 4; t2++) {
                    unsigned lo = (unsigned short)xs[swz128(k0 + 2 * t2,     d)];
                    unsigned hi = (unsigned short)xs[swz128(k0 + 2 * t2 + 1, d)];
                    bvx[nt].u[t2] = lo | (hi << 16);
                }
            }
            #pragma unroll
            for (int nt = 0; nt < 2; nt++)
                #pragma unroll
                for (int mt = 0; mt < 4; mt++)
                    accZ[nt][mt] = __builtin_amdgcn_mfma_f32_16x16x32_bf16(
                        av[mt], bvx[nt].v, accZ[nt][mt], 0, 0, 0);
        }
        __syncthreads();   // all ps reads done; as_ may overwrite the union
        #pragma unroll
        for (int mt = 0; mt < 4; mt++)
            #pragma unroll
            for (int reg = 0; reg < 4; reg++) {
                int ii = mt * 16 + quad * 4 + reg;
                #pragma unroll
                for (int nt = 0; nt < 2; nt++) {
                    int d = wid * 32 + nt * 16 + colr;
                    float zv = (ii < NN) ? accZ[nt][mt][reg] : 0.f;
                    u2.as_[swz128(ii, d)] = (short)f2bf(zv);
                }
            }
    }
    __syncthreads();

    // ---- match part: A-fragments hoisted once (64 VGPR), 16 rt-tiles ----
    bfrag8 Af[4][4];                   // [mt][ks], compile-time indexed
    #pragma unroll
    for (int ks = 0; ks < 4; ks++) {
        const int aoff = ((ks & 1) ? xo : xe) + ks * 32;
        #pragma unroll
        for (int mt = 0; mt < 4; mt++)
            Af[mt][ks] = *(const bfrag8*)(&u2.as_[aoff + mt * 2048]);
    }
    bfrag8 bfv[4];
    #pragma unroll
    for (int ks = 0; ks < 4; ks++)
        bfv[ks] = *(const bfrag8*)(Gp + (size_t)(((wid * 4 + ks) * 64 + lane) << 3));

    const int rL = wid * 16 + colr;

    #pragma unroll 2
    for (int it = 0; it < 16; it++) {
        f32x4 acc[4];
        #pragma unroll
        for (int mt = 0; mt < 4; mt++) acc[mt] = (f32x4){0.f, 0.f, 0.f, 0.f};
        #pragma unroll
        for (int ks = 0; ks < 4; ks++)
            #pragma unroll
            for (int mt = 0; mt < 4; mt++)
                acc[mt] = __builtin_amdgcn_mfma_f32_16x16x32_bf16(
                    Af[mt][ks], bfv[ks], acc[mt], 0, 0, 0);

        // prefetch next rt's B-fragments (clamped; unused on last iter)
        const int rtn = (it < 15) ? it + 1 : it;
        bfrag8 nxt[4];
        #pragma unroll
        for (int ks = 0; ks < 4; ks++)
            nxt[ks] = *(const bfrag8*)(Gp + (size_t)(((rtn * 16 + wid * 4 + ks) * 64 + lane) << 3));

        const int r  = it * 64 + rL;
        const int rc = (r < RR) ? r : (RR - 1);
        float2 cc = ((const float2*)cent)[rc];
        const float rvx = cc.x * KHALF, rvy = cc.y * KHALF;
        const float rvz = cos_small(cc.x * DEG2RADF);

        // ---- bias + softmax-weighted sum (exp2 domain; no max pass) ----
        float s[14];
        #pragma unroll
        for (int mt = 0; mt < 4; mt++) {
            const int nregs = (mt == 3) ? 2 : 4;
            #pragma unroll
            for (int reg = 0; reg < nregs; reg++) {
                int n = mt * 16 + quad * 4 + reg;
                float4 bn = bnfoM[n];
                float du = bn.x - rvx, dv = bn.y - rvy;
                float a = fmaf((bn.z * rvz) * dv, dv, du * du);
                float x = __builtin_amdgcn_sqrtf(a);
                float db = x * fmaf(a, DBIN_C1, DBIN_C0);
                int   kd = (int)db;
                float fd = fract_asm(db);
                float2 ed = Em2[kd];
                float bias = fmaf(fd, ed.y, ed.x);
                s[mt * 4 + reg] = (acc[mt][reg] + bias) + bn.w;
            }
        }
        float l = 0.f, aw = 0.f;
        #pragma unroll
        for (int t = 0; t < 14; t++) {
            float p = exp2_asm(s[t]);        // pad slots: exp2(-1e30) = 0
            l += p;
            aw = fmaf(p, s[t], aw);          // fma(0, -1e30, aw) = aw exactly
        }
        l  += __shfl_xor(l, 16, 64); aw += __shfl_xor(aw, 16, 64);
        l  += __shfl_xor(l, 32, 64); aw += __shfl_xor(aw, 32, 64);
        if (quad == 0 && r < RR)
            out[(size_t)b * RR + r] = aw * __builtin_amdgcn_rcpf(l) * LN2;

        #pragma unroll
        for (int ks = 0; ks < 4; ks++) bfv[ks] = nxt[ks];
    }
}

extern "C" void kernel_launch(void* const* d_in, const int* in_sizes, int n_in,
                              void* d_out, int out_size, void* d_ws, size_t ws_size,
                              hipStream_t stream) {
    const int*   poi_idx  = (const int*)d_in[0];
    const int*   hourw    = (const int*)d_in[1];
    const float* lat      = (const float*)d_in[2];
    const float* lon      = (const float*)d_in[3];
    const float* tmin     = (const float*)d_in[4];
    const float* cent     = (const float*)d_in[5];
    const float* poi_emb  = (const float*)d_in[6];
    const float* time_emb = (const float*)d_in[7];
    const float* E_t      = (const float*)d_in[8];
    const float* E_d      = (const float*)d_in[9];
    const float* E_dm     = (const float*)d_in[10];
    const float* Remb     = (const float*)d_in[11];
    const float* Wq       = (const float*)d_in[12];
    const float* Wk       = (const float*)d_in[13];
    const float* Wv       = (const float*)d_in[14];
    float* out            = (float*)d_out;

    unsigned short* Mtb = (unsigned short*)d_ws;            // 128*128 bf16 (32 KB)
    unsigned short* Gpb = Mtb + DD * DD;                    // 1024*128 bf16 (256 KB, frag order)

    prep_mg<<<dim3(DD + 1024), DD, 0, stream>>>(Wq, Wk, Wv, Remb, Mtb, Gpb);
    stan_fused<<<dim3(BB), 256, 0, stream>>>(poi_idx, hourw, lat, lon, tmin,
                                             poi_emb, time_emb, E_t, E_d, E_dm,
                                             Mtb, Gpb, cent, out);
}

// Round 9
// 154.271 us; speedup vs baseline: 1.6448x; 1.6448x over previous
//
#include <hip/hip_runtime.h>
#include <hip/hip_bf16.h>
#include <math.h>

// ---- problem constants ----
constexpr int BB    = 1024;
constexpr int NN    = 50;
constexpr int RR    = 1000;
constexpr int DD    = 128;
constexpr int NPOIS = 50000;
#define DEG2RADF  0.017453292519943295f
#define KHALF     0.008726646259971648f   // DEG2RAD/2
#define RSQRTD    0.08838834764831845f    // 1/sqrt(128)
#define LOG2E     1.4426950408889634f
#define LN2       0.6931471805599453f
#define DBIN_C0   4013.7373f
#define DBIN_C1   668.95621f
#define TBIN_SC   0.00625f                // 63/10080
#define PENAL     -1.0e30f                // additive mask sentinel

typedef __attribute__((ext_vector_type(8))) short bfrag8;
typedef __attribute__((ext_vector_type(4))) float f32x4;

// XOR-swizzled LDS tile addressing (shorts). Row stride 128 shorts;
// 16-B block j of row r lives at physical block j ^ (r & 7).
// All MFMA fragment-row indices are ≡ colr (mod 8), so for a fragment read of
// logical k-chunk ks the physical offset is  base + kx + ks*32  (even ks) or
// base - kx + ks*32  (odd ks), with base = colr*128 + 8*(quad^(colr&3)) and
// kx = 32*((colr>>2)&1).  Iterate LOGICAL ks: bit 2 of the physical block
// index then varies ACROSS LANES per instruction (all 32 banks covered,
// 8 lanes/bank = conflict-free minimum).  (Round 1 measured: physical-index
// iteration doubles SQ_LDS_BANK_CONFLICT.)
// REGISTER-PRESSURE NOTE (round 8 measured): the allocator pins this kernel
// at 64 VGPR and SPILLS rather than expanding toward the launch-bounds cap.
// Cross-phase fragment hoists (Xf) and match-loop unroll-2 both spilled:
// FETCH 14->460 MB, dur 74->163 us.  Do NOT add cross-barrier register state.
__device__ __forceinline__ int swz128(int row, int k) {
    return row * 128 + ((((k) >> 3) ^ (row & 7)) << 3) + (k & 7);
}

__device__ __forceinline__ unsigned short f2bf(float x) {
    union { __hip_bfloat16 h; unsigned short u; } cv;
    cv.h = __float2bfloat16(x);
    return cv.u;
}

__device__ __forceinline__ float exp2_asm(float x) {   // v_exp_f32: D = 2^S0
    float r;
    asm("v_exp_f32 %0, %1" : "=v"(r) : "v"(x));
    return r;
}

__device__ __forceinline__ float fract_asm(float x) {  // D = S0 - floor(S0)
    float r;
    asm("v_fract_f32 %0, %1" : "=v"(r) : "v"(x));
    return r;
}

__device__ __forceinline__ float cos_small(float x) {
    float x2 = x * x;
    return 1.0f - 0.5f * x2 + 0.041666667f * x2 * x2;
}

// ---- precompute (merged): Mt and Gp, both bf16 with LOG2E/sqrt(D) folded ----
// Gp in MFMA B-fragment order: Gp[rt][wid][ks][lane][8], lane = quad*16+colr,
// r = rt*64 + wid*16 + colr, k = ks*32 + quad*8 + k7. Rows 1000..1023 zeroed.
__global__ void prep_mg(const float* __restrict__ Wq, const float* __restrict__ Wk,
                        const float* __restrict__ Wv, const float* __restrict__ Re,
                        unsigned short* __restrict__ Mt, unsigned short* __restrict__ Gp) {
    int k = threadIdx.x;
    if (blockIdx.x < DD) {
        int c = blockIdx.x;
        float s0 = 0.f, s1 = 0.f, s2 = 0.f, s3 = 0.f;
        for (int d = 0; d < DD; d += 4) {
            s0 += Wq[(d + 0) * DD + k] * Wk[(d + 0) * DD + c];
            s1 += Wq[(d + 1) * DD + k] * Wk[(d + 1) * DD + c];
            s2 += Wq[(d + 2) * DD + k] * Wk[(d + 2) * DD + c];
            s3 += Wq[(d + 3) * DD + k] * Wk[(d + 3) * DD + c];
        }
        Mt[c * DD + k] = f2bf((s0 + s1 + s2 + s3) * (RSQRTD * LOG2E));
    } else {
        int r = blockIdx.x - DD;
        float val = 0.f;
        if (r < RR) {
            float s0 = 0.f, s1 = 0.f, s2 = 0.f, s3 = 0.f;
            for (int d = 0; d < DD; d += 4) {
                s0 += Wv[(d + 0) * DD + k] * Re[r * DD + d + 0];
                s1 += Wv[(d + 1) * DD + k] * Re[r * DD + d + 1];
                s2 += Wv[(d + 2) * DD + k] * Re[r * DD + d + 2];
                s3 += Wv[(d + 3) * DD + k] * Re[r * DD + d + 3];
            }
            val = (s0 + s1 + s2 + s3) * (RSQRTD * LOG2E);
        }
        int rt = r >> 6, widr = (r >> 4) & 3, colr = r & 15;
        int ks = k >> 5, quad = (k >> 3) & 3, k7 = k & 7;
        int lane = quad * 16 + colr;
        Gp[((((rt * 16 + widr * 4 + ks) * 64) + lane) << 3) + k7] = f2bf(val);
    }
}

// ---- fused: per-b attention (4 MFMA phases) + match (16 rt-tiles) ----
// Z never touches HBM: accZ registers -> swizzled LDS (reusing the dead
// ys/ps union as As) -> Af registers -> match loop.
__global__ __launch_bounds__(256, 4) void stan_fused(
    const int* __restrict__ poi_idx, const int* __restrict__ hourw,
    const float* __restrict__ lat, const float* __restrict__ lon,
    const float* __restrict__ tmin,
    const float* __restrict__ poi_emb, const float* __restrict__ time_emb,
    const float* __restrict__ Et_g, const float* __restrict__ Ed_g,
    const float* __restrict__ Em_g,
    const unsigned short* __restrict__ Mtb, const unsigned short* __restrict__ Gp,
    const float* __restrict__ cent, float* __restrict__ out) {
    __shared__ short xs[64 * 128];             // x bf16, swizzled, 16 KB
    __shared__ union {
        short ys[64 * 128];                    // Y bf16, swizzled, 16 KB
        short ps[64 * 64];                     // P bf16, swizzled
        short as_[64 * 128];                   // Z bf16, swizzled (match A-tile)
    } u2;
    __shared__ float2 Et2[64], Ed2[64], Em2[64];  // (e, de) * LOG2E
    __shared__ float4 bnfo[64];                // (latk, lonk, cos, t*TBIN_SC)
    __shared__ float4 bnfoM[64];               // (latk, lonk, cos, pen) for match
    __shared__ float  jpen[64];                // 0 valid / -1e30 pad
    __shared__ int2   nidx[64];                // (poi row, hour row) for gather

    const int b = blockIdx.x, tid = threadIdx.x;
    const int wid = tid >> 6, lane = tid & 63;
    const int quad = lane >> 4, colr = lane & 15;

    if (tid < 64) {
        int kk = tid > 62 ? 62 : tid;
        float t0 = Et_g[kk] * LOG2E, t1 = Et_g[kk + 1] * LOG2E;
        float d0 = Ed_g[kk] * LOG2E, d1 = Ed_g[kk + 1] * LOG2E;
        float e0 = Em_g[kk] * LOG2E, e1 = Em_g[kk + 1] * LOG2E;
        Et2[tid] = make_float2(t0, t1 - t0);
        Ed2[tid] = make_float2(d0, d1 - d0);
        Em2[tid] = make_float2(e0, e1 - e0);
        if (tid < NN) {
            int p = poi_idx[b * NN + tid];
            int pd = (p < 0);
            float la = lat[b * NN + tid], lo = lon[b * NN + tid];
            float cs = cos_small(la * DEG2RADF);
            float pen = pd ? PENAL : 0.f;
            nidx[tid] = make_int2(pd ? NPOIS : p, pd ? 0 : hourw[b * NN + tid]);
            bnfo[tid]  = make_float4(la * KHALF, lo * KHALF, cs,
                                     tmin[b * NN + tid] * TBIN_SC);
            bnfoM[tid] = make_float4(la * KHALF, lo * KHALF, cs, pen);
            jpen[tid] = pen;
        } else {
            // poi_emb[NPOIS] and time_emb[0] are all-zero rows -> x row = 0
            nidx[tid] = make_int2(NPOIS, 0);
            bnfo[tid]  = make_float4(0.f, 0.f, 1.f, 0.f);
            bnfoM[tid] = make_float4(0.f, 0.f, 1.f, PENAL);
            jpen[tid] = PENAL;
        }
    }
    __syncthreads();

    // ---- phase 1: gather x -> xs (bf16, swizzled u32 stores) ----
    for (int idx = tid; idx < 64 * 64; idx += 256) {
        int n = idx >> 6, c2 = idx & 63;       // c2 = dword index within row
        int2 ix = nidx[n];
        float2 pe = ((const float2*)(poi_emb  + (size_t)ix.x * DD))[c2];
        float2 te = ((const float2*)(time_emb + (size_t)ix.y * DD))[c2];
        unsigned pack = (unsigned)f2bf(pe.x + te.x)
                      | ((unsigned)f2bf(pe.y + te.y) << 16);
        ((unsigned*)xs)[n * 64 + (((c2 >> 2) ^ (n & 7)) << 2) + (c2 & 3)] = pack;
    }
    __syncthreads();

    // thread-constant swizzle bases (see comment at swz128)
    const int q8    = (quad ^ (colr & 3)) * 8;
    const int kx    = (colr & 4) * 8;          // ((colr>>2)&1)*32
    const int xbase = colr * 128 + q8;
    const int xe = xbase + kx, xo = xbase - kx;

    // ---- phase 2: Y = x @ Mt^T (MFMA), Mt streamed from L1/L2 ----
    {
        f32x4 accY[2][4];
        #pragma unroll
        for (int ct = 0; ct < 2; ct++)
            #pragma unroll
            for (int mt = 0; mt < 4; mt++) accY[ct][mt] = (f32x4){0.f, 0.f, 0.f, 0.f};
        #pragma unroll
        for (int ks = 0; ks < 4; ks++) {
            const int k0 = ks * 32 + quad * 8;                 // logical (global Mt read)
            const int xoff = ((ks & 1) ? xo : xe) + ks * 32;   // physical LDS offset
            bfrag8 av[4], bv[2];
            #pragma unroll
            for (int mt = 0; mt < 4; mt++)
                av[mt] = *(const bfrag8*)(&xs[xoff + mt * 2048]);
            #pragma unroll
            for (int ct = 0; ct < 2; ct++) {
                int c = wid * 32 + ct * 16 + colr;
                bv[ct] = *(const bfrag8*)(Mtb + (size_t)c * DD + k0);
            }
            #pragma unroll
            for (int ct = 0; ct < 2; ct++)
                #pragma unroll
                for (int mt = 0; mt < 4; mt++)
                    accY[ct][mt] = __builtin_amdgcn_mfma_f32_16x16x32_bf16(
                        av[mt], bv[ct], accY[ct][mt], 0, 0, 0);
        }
        #pragma unroll
        for (int ct = 0; ct < 2; ct++)
            #pragma unroll
            for (int mt = 0; mt < 4; mt++)
                #pragma unroll
                for (int reg = 0; reg < 4; reg++) {
                    int m = mt * 16 + quad * 4 + reg;
                    int c = wid * 32 + ct * 16 + colr;
                    u2.ys[swz128(m, c)] = (short)f2bf(accY[ct][mt][reg]);
                }
    }
    __syncthreads();

    // ---- phase 3: S^T = x @ Y^T (MFMA). C: row=j, col=i=wid*16+colr ----
    const int i = wid * 16 + colr;
    const int ybase = xbase + wid * 2048;
    const int ye = ybase + kx, yo = ybase - kx;
    f32x4 accS[4];
    #pragma unroll
    for (int mt = 0; mt < 4; mt++) accS[mt] = (f32x4){0.f, 0.f, 0.f, 0.f};
    #pragma unroll
    for (int ks = 0; ks < 4; ks++) {           // LOGICAL order: conflict-free
        const int yoff = ((ks & 1) ? yo : ye) + ks * 32;
        const int xoff = ((ks & 1) ? xo : xe) + ks * 32;
        bfrag8 bv = *(const bfrag8*)(&u2.ys[yoff]);
        #pragma unroll
        for (int mt = 0; mt < 4; mt++) {
            bfrag8 av = *(const bfrag8*)(&xs[xoff + mt * 2048]);
            accS[mt] = __builtin_amdgcn_mfma_f32_16x16x32_bf16(
                av, bv, accS[mt], 0, 0, 0);
        }
    }
    __syncthreads();   // ys MFMA reads done; ps may overwrite the union

    // ---- bias + softmax over j (exp2 domain; NO max pass: scores are O(1),
    // pads give exp2(-1e30)=0 exactly; f32 exp2 safe to |s|~120) ----
    {
        const float4 bi = bnfo[i];
        float sv[14];
        #pragma unroll
        for (int mt = 0; mt < 4; mt++) {
            const int nregs = (mt == 3) ? 2 : 4;
            #pragma unroll
            for (int reg = 0; reg < nregs; reg++) {
                int j = mt * 16 + quad * 4 + reg;
                float4 bj = bnfo[j];
                float tb = fabsf(bi.w - bj.w);
                int   kt = (int)tb;
                float ft = fract_asm(tb);
                float2 et = Et2[kt];
                float bt = fmaf(ft, et.y, et.x);
                float du = bi.x - bj.x, dv = bi.y - bj.y;
                float a = fmaf((bi.z * bj.z) * dv, dv, du * du);
                float x = __builtin_amdgcn_sqrtf(a);
                float db = x * fmaf(a, DBIN_C1, DBIN_C0);
                int   kd = (int)db;
                float fd = fract_asm(db);
                float2 ed = Ed2[kd];
                float bd = fmaf(fd, ed.y, ed.x);
                sv[mt * 4 + reg] = (accS[mt][reg] + bt) + (bd + jpen[j]);
            }
        }
        float l = 0.f;
        #pragma unroll
        for (int t = 0; t < 14; t++) {
            float p = exp2_asm(sv[t]);
            sv[t] = p;
            l += p;
        }
        l += __shfl_xor(l, 16, 64);
        l += __shfl_xor(l, 32, 64);
        float rl = __builtin_amdgcn_rcpf(l);
        #pragma unroll
        for (int mt = 0; mt < 4; mt++)
            #pragma unroll
            for (int rp = 0; rp < 2; rp++) {
                int j0 = mt * 16 + quad * 4 + rp * 2;
                unsigned pack;
                if (mt == 3 && rp == 1) {
                    pack = 0u;                 // always-invalid slots: P = 0
                } else {
                    unsigned lo = f2bf(sv[mt * 4 + rp * 2]     * rl);
                    unsigned hi = f2bf(sv[mt * 4 + rp * 2 + 1] * rl);
                    pack = lo | (hi << 16);
                }
                ((unsigned*)u2.ps)[i * 32 + (((j0 >> 3) ^ (i & 7)) << 2) + ((j0 & 7) >> 1)]
                    = pack;
            }
    }
    __syncthreads();

    // ---- phase 4: Z = P @ x (K=64 over j); then accZ -> As (swizzled LDS) ----
    {
        f32x4 accZ[2][4];
        #pragma unroll
        for (int nt = 0; nt < 2; nt++)
            #pragma unroll
            for (int mt = 0; mt < 4; mt++) accZ[nt][mt] = (f32x4){0.f, 0.f, 0.f, 0.f};
        union BF { unsigned u[4]; bfrag8 v; };
        const int pbase = colr * 64 + q8;
        const int pe = pbase + kx, po = pbase - kx;
        #pragma unroll
        for (int ks = 0; ks < 2; ks++) {
            const int k0 = ks * 32 + quad * 8;                 // logical (xs gather)
            const int poff = ((ks & 1) ? po : pe) + ks * 32;   // physical (ps reads)
            bfrag8 av[4];
            #pragma unroll
            for (int mt = 0; mt < 4; mt++)
                av[mt] = *(const bfrag8*)(&u2.ps[poff + mt * 1024]);
            BF bvx[2];
            #pragma unroll
            for (int nt = 0; nt < 2; nt++) {
                int d = wid * 32 + nt * 16 + colr;
                #pragma unroll
                for (int t2 = 0; t2 < 4; t2++) {
                    unsigned lo = (unsigned short)xs[swz128(k0 + 2 * t2,     d)];
                    unsigned hi = (unsigned short)xs[swz128(k0 + 2 * t2 + 1, d)];
                    bvx[nt].u[t2] = lo | (hi << 16);
                }
            }
            #pragma unroll
            for (int nt = 0; nt < 2; nt++)
                #pragma unroll
                for (int mt = 0; mt < 4; mt++)
                    accZ[nt][mt] = __builtin_amdgcn_mfma_f32_16x16x32_bf16(
                        av[mt], bvx[nt].v, accZ[nt][mt], 0, 0, 0);
        }
        __syncthreads();   // all ps reads done; as_ may overwrite the union
        #pragma unroll
        for (int mt = 0; mt < 4; mt++)
            #pragma unroll
            for (int reg = 0; reg < 4; reg++) {
                int ii = mt * 16 + quad * 4 + reg;
                #pragma unroll
                for (int nt = 0; nt < 2; nt++) {
                    int d = wid * 32 + nt * 16 + colr;
                    float zv = (ii < NN) ? accZ[nt][mt][reg] : 0.f;
                    u2.as_[swz128(ii, d)] = (short)f2bf(zv);
                }
            }
    }
    __syncthreads();

    // ---- match part: A-fragments hoisted once (64 VGPR), 16 rt-tiles ----
    bfrag8 Af[4][4];                   // [mt][ks], compile-time indexed
    #pragma unroll
    for (int ks = 0; ks < 4; ks++) {
        const int aoff = ((ks & 1) ? xo : xe) + ks * 32;
        #pragma unroll
        for (int mt = 0; mt < 4; mt++)
            Af[mt][ks] = *(const bfrag8*)(&u2.as_[aoff + mt * 2048]);
    }
    bfrag8 bfv[4];
    #pragma unroll
    for (int ks = 0; ks < 4; ks++)
        bfv[ks] = *(const bfrag8*)(Gp + (size_t)(((wid * 4 + ks) * 64 + lane) << 3));

    const int rL = wid * 16 + colr;

    #pragma unroll 1
    for (int it = 0; it < 16; it++) {
        f32x4 acc[4];
        #pragma unroll
        for (int mt = 0; mt < 4; mt++) acc[mt] = (f32x4){0.f, 0.f, 0.f, 0.f};
        #pragma unroll
        for (int ks = 0; ks < 4; ks++)
            #pragma unroll
            for (int mt = 0; mt < 4; mt++)
                acc[mt] = __builtin_amdgcn_mfma_f32_16x16x32_bf16(
                    Af[mt][ks], bfv[ks], acc[mt], 0, 0, 0);

        // prefetch next rt's B-fragments (clamped; unused on last iter)
        const int rtn = (it < 15) ? it + 1 : it;
        bfrag8 nxt[4];
        #pragma unroll
        for (int ks = 0; ks < 4; ks++)
            nxt[ks] = *(const bfrag8*)(Gp + (size_t)(((rtn * 16 + wid * 4 + ks) * 64 + lane) << 3));

        const int r  = it * 64 + rL;
        const int rc = (r < RR) ? r : (RR - 1);
        float2 cc = ((const float2*)cent)[rc];
        const float rvx = cc.x * KHALF, rvy = cc.y * KHALF;
        const float rvz = cos_small(cc.x * DEG2RADF);

        // ---- bias + softmax-weighted sum (exp2 domain; no max pass) ----
        float s[14];
        #pragma unroll
        for (int mt = 0; mt < 4; mt++) {
            const int nregs = (mt == 3) ? 2 : 4;
            #pragma unroll
            for (int reg = 0; reg < nregs; reg++) {
                int n = mt * 16 + quad * 4 + reg;
                float4 bn = bnfoM[n];
                float du = bn.x - rvx, dv = bn.y - rvy;
                float a = fmaf((bn.z * rvz) * dv, dv, du * du);
                float x = __builtin_amdgcn_sqrtf(a);
                float db = x * fmaf(a, DBIN_C1, DBIN_C0);
                int   kd = (int)db;
                float fd = fract_asm(db);
                float2 ed = Em2[kd];
                float bias = fmaf(fd, ed.y, ed.x);
                s[mt * 4 + reg] = (acc[mt][reg] + bias) + bn.w;
            }
        }
        float l = 0.f, aw = 0.f;
        #pragma unroll
        for (int t = 0; t < 14; t++) {
            float p = exp2_asm(s[t]);        // pad slots: exp2(-1e30) = 0
            l += p;
            aw = fmaf(p, s[t], aw);          // fma(0, -1e30, aw) = aw exactly
        }
        l  += __shfl_xor(l, 16, 64); aw += __shfl_xor(aw, 16, 64);
        l  += __shfl_xor(l, 32, 64); aw += __shfl_xor(aw, 32, 64);
        if (quad == 0 && r < RR)
            out[(size_t)b * RR + r] = aw * __builtin_amdgcn_rcpf(l) * LN2;

        #pragma unroll
        for (int ks = 0; ks < 4; ks++) bfv[ks] = nxt[ks];
    }
}

extern "C" void kernel_launch(void* const* d_in, const int* in_sizes, int n_in,
                              void* d_out, int out_size, void* d_ws, size_t ws_size,
                              hipStream_t stream) {
    const int*   poi_idx  = (const int*)d_in[0];
    const int*   hourw    = (const int*)d_in[1];
    const float* lat      = (const float*)d_in[2];
    const float* lon      = (const float*)d_in[3];
    const float* tmin     = (const float*)d_in[4];
    const float* cent     = (const float*)d_in[5];
    const float* poi_emb  = (const float*)d_in[6];
    const float* time_emb = (const float*)d_in[7];
    const float* E_t      = (const float*)d_in[8];
    const float* E_d      = (const float*)d_in[9];
    const float* E_dm     = (const float*)d_in[10];
    const float* Remb     = (const float*)d_in[11];
    const float* Wq       = (const float*)d_in[12];
    const float* Wk       = (const float*)d_in[13];
    const float* Wv       = (const float*)d_in[14];
    float* out            = (float*)d_out;

    unsigned short* Mtb = (unsigned short*)d_ws;            // 128*128 bf16 (32 KB)
    unsigned short* Gpb = Mtb + DD * DD;                    // 1024*128 bf16 (256 KB, frag order)

    prep_mg<<<dim3(DD + 1024), DD, 0, stream>>>(Wq, Wk, Wv, Remb, Mtb, Gpb);
    stan_fused<<<dim3(BB), 256, 0, stream>>>(poi_idx, hourw, lat, lon, tmin,
                                             poi_emb, time_emb, E_t, E_d, E_dm,
                                             Mtb, Gpb, cent, out);
}

// Round 10
// 152.432 us; speedup vs baseline: 1.6646x; 1.0121x over previous
//
#include <hip/hip_runtime.h>
#include <hip/hip_bf16.h>
#include <math.h>

// ---- problem constants ----
constexpr int BB    = 1024;
constexpr int NN    = 50;
constexpr int RR    = 1000;
constexpr int DD    = 128;
constexpr int NPOIS = 50000;
#define DEG2RADF  0.017453292519943295f
#define KHALF     0.008726646259971648f   // DEG2RAD/2
#define RSQRTD    0.08838834764831845f    // 1/sqrt(128)
#define LOG2E     1.4426950408889634f
#define LN2       0.6931471805599453f
#define DBIN_C0   4013.7373f
#define DBIN_C1   668.95621f
#define TBIN_SC   0.00625f                // 63/10080
#define PENAL     -1.0e30f                // additive mask sentinel

typedef __attribute__((ext_vector_type(8))) short bfrag8;
typedef __attribute__((ext_vector_type(4))) float f32x4;

// XOR-swizzled LDS tile addressing (shorts). Row stride 128 shorts;
// 16-B block j of row r lives at physical block j ^ (r & 7).
// All MFMA fragment-row indices are ≡ colr (mod 8), so for a fragment read of
// logical k-chunk ks the physical offset is  base + kx + ks*32  (even ks) or
// base - kx + ks*32  (odd ks), with base = colr*128 + 8*(quad^(colr&3)) and
// kx = 32*((colr>>2)&1).  Iterate LOGICAL ks: bit 2 of the physical block
// index then varies ACROSS LANES per instruction (all 32 banks covered,
// 8 lanes/bank = conflict-free minimum).  (Round 1 measured: physical-index
// iteration doubles SQ_LDS_BANK_CONFLICT.)
// REGISTER-PRESSURE NOTE (rounds 8/9 measured): the allocator pins at 64 VGPR
// and demotes/spills rather than allocating 65-128.  Round 8: Xf hoist +
// unroll-2 (demand >>128) -> scratch spill, FETCH 14->460 MB.  Round 9:
// Af+acc+bfv+nxt demand ~132 -> Af silently demoted to per-iter LDS re-reads
// (VGPR_Count 64).  Keep total register demand <= ~110 so Af can live in
// registers: single-buffer bfv, no s[] array, no cross-barrier hoists.
__device__ __forceinline__ int swz128(int row, int k) {
    return row * 128 + ((((k) >> 3) ^ (row & 7)) << 3) + (k & 7);
}

__device__ __forceinline__ unsigned short f2bf(float x) {
    union { __hip_bfloat16 h; unsigned short u; } cv;
    cv.h = __float2bfloat16(x);
    return cv.u;
}

__device__ __forceinline__ float exp2_asm(float x) {   // v_exp_f32: D = 2^S0
    float r;
    asm("v_exp_f32 %0, %1" : "=v"(r) : "v"(x));
    return r;
}

__device__ __forceinline__ float fract_asm(float x) {  // D = S0 - floor(S0)
    float r;
    asm("v_fract_f32 %0, %1" : "=v"(r) : "v"(x));
    return r;
}

__device__ __forceinline__ float cos_small(float x) {
    float x2 = x * x;
    return 1.0f - 0.5f * x2 + 0.041666667f * x2 * x2;
}

// ---- precompute (merged): Mt and Gp, both bf16 with LOG2E/sqrt(D) folded ----
// Gp in MFMA B-fragment order: Gp[rt][wid][ks][lane][8], lane = quad*16+colr,
// r = rt*64 + wid*16 + colr, k = ks*32 + quad*8 + k7. Rows 1000..1023 zeroed.
__global__ void prep_mg(const float* __restrict__ Wq, const float* __restrict__ Wk,
                        const float* __restrict__ Wv, const float* __restrict__ Re,
                        unsigned short* __restrict__ Mt, unsigned short* __restrict__ Gp) {
    int k = threadIdx.x;
    if (blockIdx.x < DD) {
        int c = blockIdx.x;
        float s0 = 0.f, s1 = 0.f, s2 = 0.f, s3 = 0.f;
        for (int d = 0; d < DD; d += 4) {
            s0 += Wq[(d + 0) * DD + k] * Wk[(d + 0) * DD + c];
            s1 += Wq[(d + 1) * DD + k] * Wk[(d + 1) * DD + c];
            s2 += Wq[(d + 2) * DD + k] * Wk[(d + 2) * DD + c];
            s3 += Wq[(d + 3) * DD + k] * Wk[(d + 3) * DD + c];
        }
        Mt[c * DD + k] = f2bf((s0 + s1 + s2 + s3) * (RSQRTD * LOG2E));
    } else {
        int r = blockIdx.x - DD;
        float val = 0.f;
        if (r < RR) {
            float s0 = 0.f, s1 = 0.f, s2 = 0.f, s3 = 0.f;
            for (int d = 0; d < DD; d += 4) {
                s0 += Wv[(d + 0) * DD + k] * Re[r * DD + d + 0];
                s1 += Wv[(d + 1) * DD + k] * Re[r * DD + d + 1];
                s2 += Wv[(d + 2) * DD + k] * Re[r * DD + d + 2];
                s3 += Wv[(d + 3) * DD + k] * Re[r * DD + d + 3];
            }
            val = (s0 + s1 + s2 + s3) * (RSQRTD * LOG2E);
        }
        int rt = r >> 6, widr = (r >> 4) & 3, colr = r & 15;
        int ks = k >> 5, quad = (k >> 3) & 3, k7 = k & 7;
        int lane = quad * 16 + colr;
        Gp[((((rt * 16 + widr * 4 + ks) * 64) + lane) << 3) + k7] = f2bf(val);
    }
}

// ---- fused: per-b attention (4 MFMA phases) + match (16 rt-tiles) ----
// Z never touches HBM: accZ registers -> swizzled LDS (reusing the dead
// ys/ps union as As) -> Af registers -> match loop.
__global__ __launch_bounds__(256, 4) void stan_fused(
    const int* __restrict__ poi_idx, const int* __restrict__ hourw,
    const float* __restrict__ lat, const float* __restrict__ lon,
    const float* __restrict__ tmin,
    const float* __restrict__ poi_emb, const float* __restrict__ time_emb,
    const float* __restrict__ Et_g, const float* __restrict__ Ed_g,
    const float* __restrict__ Em_g,
    const unsigned short* __restrict__ Mtb, const unsigned short* __restrict__ Gp,
    const float* __restrict__ cent, float* __restrict__ out) {
    __shared__ short xs[64 * 128];             // x bf16, swizzled, 16 KB
    __shared__ union {
        short ys[64 * 128];                    // Y bf16, swizzled, 16 KB
        short ps[64 * 64];                     // P bf16, swizzled
        short as_[64 * 128];                   // Z bf16, swizzled (match A-tile)
    } u2;
    __shared__ float2 Et2[64], Ed2[64], Em2[64];  // (e, de) * LOG2E
    __shared__ float4 bnfo[64];                // (latk, lonk, cos, t*TBIN_SC)
    __shared__ float4 bnfoM[64];               // (latk, lonk, cos, pen) for match
    __shared__ float  jpen[64];                // 0 valid / -1e30 pad
    __shared__ int2   nidx[64];                // (poi row, hour row) for gather

    const int b = blockIdx.x, tid = threadIdx.x;
    const int wid = tid >> 6, lane = tid & 63;
    const int quad = lane >> 4, colr = lane & 15;

    if (tid < 64) {
        int kk = tid > 62 ? 62 : tid;
        float t0 = Et_g[kk] * LOG2E, t1 = Et_g[kk + 1] * LOG2E;
        float d0 = Ed_g[kk] * LOG2E, d1 = Ed_g[kk + 1] * LOG2E;
        float e0 = Em_g[kk] * LOG2E, e1 = Em_g[kk + 1] * LOG2E;
        Et2[tid] = make_float2(t0, t1 - t0);
        Ed2[tid] = make_float2(d0, d1 - d0);
        Em2[tid] = make_float2(e0, e1 - e0);
        if (tid < NN) {
            int p = poi_idx[b * NN + tid];
            int pd = (p < 0);
            float la = lat[b * NN + tid], lo = lon[b * NN + tid];
            float cs = cos_small(la * DEG2RADF);
            float pen = pd ? PENAL : 0.f;
            nidx[tid] = make_int2(pd ? NPOIS : p, pd ? 0 : hourw[b * NN + tid]);
            bnfo[tid]  = make_float4(la * KHALF, lo * KHALF, cs,
                                     tmin[b * NN + tid] * TBIN_SC);
            bnfoM[tid] = make_float4(la * KHALF, lo * KHALF, cs, pen);
            jpen[tid] = pen;
        } else {
            // poi_emb[NPOIS] and time_emb[0] are all-zero rows -> x row = 0
            nidx[tid] = make_int2(NPOIS, 0);
            bnfo[tid]  = make_float4(0.f, 0.f, 1.f, 0.f);
            bnfoM[tid] = make_float4(0.f, 0.f, 1.f, PENAL);
            jpen[tid] = PENAL;
        }
    }
    __syncthreads();

    // ---- phase 1: gather x -> xs (bf16, swizzled u32 stores) ----
    for (int idx = tid; idx < 64 * 64; idx += 256) {
        int n = idx >> 6, c2 = idx & 63;       // c2 = dword index within row
        int2 ix = nidx[n];
        float2 pe = ((const float2*)(poi_emb  + (size_t)ix.x * DD))[c2];
        float2 te = ((const float2*)(time_emb + (size_t)ix.y * DD))[c2];
        unsigned pack = (unsigned)f2bf(pe.x + te.x)
                      | ((unsigned)f2bf(pe.y + te.y) << 16);
        ((unsigned*)xs)[n * 64 + (((c2 >> 2) ^ (n & 7)) << 2) + (c2 & 3)] = pack;
    }
    __syncthreads();

    // thread-constant swizzle bases (see comment at swz128)
    const int q8    = (quad ^ (colr & 3)) * 8;
    const int kx    = (colr & 4) * 8;          // ((colr>>2)&1)*32
    const int xbase = colr * 128 + q8;
    const int xe = xbase + kx, xo = xbase - kx;

    // ---- phase 2: Y = x @ Mt^T (MFMA), Mt streamed from L1/L2 ----
    {
        f32x4 accY[2][4];
        #pragma unroll
        for (int ct = 0; ct < 2; ct++)
            #pragma unroll
            for (int mt = 0; mt < 4; mt++) accY[ct][mt] = (f32x4){0.f, 0.f, 0.f, 0.f};
        #pragma unroll
        for (int ks = 0; ks < 4; ks++) {
            const int k0 = ks * 32 + quad * 8;                 // logical (global Mt read)
            const int xoff = ((ks & 1) ? xo : xe) + ks * 32;   // physical LDS offset
            bfrag8 av[4], bv[2];
            #pragma unroll
            for (int mt = 0; mt < 4; mt++)
                av[mt] = *(const bfrag8*)(&xs[xoff + mt * 2048]);
            #pragma unroll
            for (int ct = 0; ct < 2; ct++) {
                int c = wid * 32 + ct * 16 + colr;
                bv[ct] = *(const bfrag8*)(Mtb + (size_t)c * DD + k0);
            }
            #pragma unroll
            for (int ct = 0; ct < 2; ct++)
                #pragma unroll
                for (int mt = 0; mt < 4; mt++)
                    accY[ct][mt] = __builtin_amdgcn_mfma_f32_16x16x32_bf16(
                        av[mt], bv[ct], accY[ct][mt], 0, 0, 0);
        }
        #pragma unroll
        for (int ct = 0; ct < 2; ct++)
            #pragma unroll
            for (int mt = 0; mt < 4; mt++)
                #pragma unroll
                for (int reg = 0; reg < 4; reg++) {
                    int m = mt * 16 + quad * 4 + reg;
                    int c = wid * 32 + ct * 16 + colr;
                    u2.ys[swz128(m, c)] = (short)f2bf(accY[ct][mt][reg]);
                }
    }
    __syncthreads();

    // ---- phase 3: S^T = x @ Y^T (MFMA). C: row=j, col=i=wid*16+colr ----
    const int i = wid * 16 + colr;
    const int ybase = xbase + wid * 2048;
    const int ye = ybase + kx, yo = ybase - kx;
    f32x4 accS[4];
    #pragma unroll
    for (int mt = 0; mt < 4; mt++) accS[mt] = (f32x4){0.f, 0.f, 0.f, 0.f};
    #pragma unroll
    for (int ks = 0; ks < 4; ks++) {           // LOGICAL order: conflict-free
        const int yoff = ((ks & 1) ? yo : ye) + ks * 32;
        const int xoff = ((ks & 1) ? xo : xe) + ks * 32;
        bfrag8 bv = *(const bfrag8*)(&u2.ys[yoff]);
        #pragma unroll
        for (int mt = 0; mt < 4; mt++) {
            bfrag8 av = *(const bfrag8*)(&xs[xoff + mt * 2048]);
            accS[mt] = __builtin_amdgcn_mfma_f32_16x16x32_bf16(
                av, bv, accS[mt], 0, 0, 0);
        }
    }
    __syncthreads();   // ys MFMA reads done; ps may overwrite the union

    // ---- bias + softmax over j (exp2 domain; NO max pass: scores are O(1),
    // pads give exp2(-1e30)=0 exactly; f32 exp2 safe to |s|~120) ----
    {
        const float4 bi = bnfo[i];
        float sv[14];
        #pragma unroll
        for (int mt = 0; mt < 4; mt++) {
            const int nregs = (mt == 3) ? 2 : 4;
            #pragma unroll
            for (int reg = 0; reg < nregs; reg++) {
                int j = mt * 16 + quad * 4 + reg;
                float4 bj = bnfo[j];
                float tb = fabsf(bi.w - bj.w);
                int   kt = (int)tb;
                float ft = fract_asm(tb);
                float2 et = Et2[kt];
                float bt = fmaf(ft, et.y, et.x);
                float du = bi.x - bj.x, dv = bi.y - bj.y;
                float a = fmaf((bi.z * bj.z) * dv, dv, du * du);
                float x = __builtin_amdgcn_sqrtf(a);
                float db = x * fmaf(a, DBIN_C1, DBIN_C0);
                int   kd = (int)db;
                float fd = fract_asm(db);
                float2 ed = Ed2[kd];
                float bd = fmaf(fd, ed.y, ed.x);
                sv[mt * 4 + reg] = (accS[mt][reg] + bt) + (bd + jpen[j]);
            }
        }
        float l = 0.f;
        #pragma unroll
        for (int t = 0; t < 14; t++) {
            float p = exp2_asm(sv[t]);
            sv[t] = p;
            l += p;
        }
        l += __shfl_xor(l, 16, 64);
        l += __shfl_xor(l, 32, 64);
        float rl = __builtin_amdgcn_rcpf(l);
        #pragma unroll
        for (int mt = 0; mt < 4; mt++)
            #pragma unroll
            for (int rp = 0; rp < 2; rp++) {
                int j0 = mt * 16 + quad * 4 + rp * 2;
                unsigned pack;
                if (mt == 3 && rp == 1) {
                    pack = 0u;                 // always-invalid slots: P = 0
                } else {
                    unsigned lo = f2bf(sv[mt * 4 + rp * 2]     * rl);
                    unsigned hi = f2bf(sv[mt * 4 + rp * 2 + 1] * rl);
                    pack = lo | (hi << 16);
                }
                ((unsigned*)u2.ps)[i * 32 + (((j0 >> 3) ^ (i & 7)) << 2) + ((j0 & 7) >> 1)]
                    = pack;
            }
    }
    __syncthreads();

    // ---- phase 4: Z = P @ x (K=64 over j); then accZ -> As (swizzled LDS) ----
    {
        f32x4 accZ[2][4];
        #pragma unroll
        for (int nt = 0; nt < 2; nt++)
            #pragma unroll
            for (int mt = 0; mt < 4; mt++) accZ[nt][mt] = (f32x4){0.f, 0.f, 0.f, 0.f};
        union BF { unsigned u[4]; bfrag8 v; };
        const int pbase = colr * 64 + q8;
        const int pe = pbase + kx, po = pbase - kx;
        #pragma unroll
        for (int ks = 0; ks < 2; ks++) {
            const int k0 = ks * 32 + quad * 8;                 // logical (xs gather)
            const int poff = ((ks & 1) ? po : pe) + ks * 32;   // physical (ps reads)
            bfrag8 av[4];
            #pragma unroll
            for (int mt = 0; mt < 4; mt++)
                av[mt] = *(const bfrag8*)(&u2.ps[poff + mt * 1024]);
            BF bvx[2];
            #pragma unroll
            for (int nt = 0; nt < 2; nt++) {
                int d = wid * 32 + nt * 16 + colr;
                #pragma unroll
                for (int t2 = 0; t2 < 4; t2++) {
                    unsigned lo = (unsigned short)xs[swz128(k0 + 2 * t2,     d)];
                    unsigned hi = (unsigned short)xs[swz128(k0 + 2 * t2 + 1, d)];
                    bvx[nt].u[t2] = lo | (hi << 16);
                }
            }
            #pragma unroll
            for (int nt = 0; nt < 2; nt++)
                #pragma unroll
                for (int mt = 0; mt < 4; mt++)
                    accZ[nt][mt] = __builtin_amdgcn_mfma_f32_16x16x32_bf16(
                        av[mt], bvx[nt].v, accZ[nt][mt], 0, 0, 0);
        }
        __syncthreads();   // all ps reads done; as_ may overwrite the union
        #pragma unroll
        for (int mt = 0; mt < 4; mt++)
            #pragma unroll
            for (int reg = 0; reg < 4; reg++) {
                int ii = mt * 16 + quad * 4 + reg;
                #pragma unroll
                for (int nt = 0; nt < 2; nt++) {
                    int d = wid * 32 + nt * 16 + colr;
                    float zv = (ii < NN) ? accZ[nt][mt][reg] : 0.f;
                    u2.as_[swz128(ii, d)] = (short)f2bf(zv);
                }
            }
    }
    __syncthreads();

    // ---- match part: Af in REGISTERS (demand kept <=~110 so the allocator
    // does not demote it back to LDS — see pressure note at top), 16 rt-tiles,
    // single-buffered B prefetch (loads issued after the MFMA cluster fly
    // under the ~500-cyc bias/softmax and land before the next cluster) ----
    bfrag8 Af[4][4];                   // [mt][ks], compile-time indexed
    #pragma unroll
    for (int ks = 0; ks < 4; ks++) {
        const int aoff = ((ks & 1) ? xo : xe) + ks * 32;
        #pragma unroll
        for (int mt = 0; mt < 4; mt++)
            Af[mt][ks] = *(const bfrag8*)(&u2.as_[aoff + mt * 2048]);
    }
    bfrag8 bfv[4];
    #pragma unroll
    for (int ks = 0; ks < 4; ks++)
        bfv[ks] = *(const bfrag8*)(Gp + (size_t)(((wid * 4 + ks) * 64 + lane) << 3));

    const int rL = wid * 16 + colr;

    #pragma unroll 1
    for (int it = 0; it < 16; it++) {
        f32x4 acc[4];
        #pragma unroll
        for (int mt = 0; mt < 4; mt++) acc[mt] = (f32x4){0.f, 0.f, 0.f, 0.f};
        #pragma unroll
        for (int ks = 0; ks < 4; ks++)
            #pragma unroll
            for (int mt = 0; mt < 4; mt++)
                acc[mt] = __builtin_amdgcn_mfma_f32_16x16x32_bf16(
                    Af[mt][ks], bfv[ks], acc[mt], 0, 0, 0);

        // bfv is dead now — reload it directly for the next tile (no double
        // buffer: 16 fewer live VGPRs than the nxt[]+rotate form)
        {
            const int rtn = (it < 15) ? it + 1 : it;
            #pragma unroll
            for (int ks = 0; ks < 4; ks++)
                bfv[ks] = *(const bfrag8*)(Gp + (size_t)(((rtn * 16 + wid * 4 + ks) * 64 + lane) << 3));
        }

        const int r  = it * 64 + rL;
        const int rc = (r < RR) ? r : (RR - 1);
        float2 cc = ((const float2*)cent)[rc];
        const float rvx = cc.x * KHALF, rvy = cc.y * KHALF;
        const float rvz = cos_small(cc.x * DEG2RADF);

        // ---- bias + softmax-weighted sum, fused single pass (exp2 domain;
        // no max pass; no s[] array -> 13 fewer live VGPRs) ----
        float l = 0.f, aw = 0.f;
        #pragma unroll
        for (int mt = 0; mt < 4; mt++) {
            const int nregs = (mt == 3) ? 2 : 4;
            #pragma unroll
            for (int reg = 0; reg < nregs; reg++) {
                int n = mt * 16 + quad * 4 + reg;
                float4 bn = bnfoM[n];
                float du = bn.x - rvx, dv = bn.y - rvy;
                float a = fmaf((bn.z * rvz) * dv, dv, du * du);
                float x = __builtin_amdgcn_sqrtf(a);
                float db = x * fmaf(a, DBIN_C1, DBIN_C0);
                int   kd = (int)db;
                float fd = fract_asm(db);
                float2 ed = Em2[kd];
                float bias = fmaf(fd, ed.y, ed.x);
                float sc = (acc[mt][reg] + bias) + bn.w;
                float p = exp2_asm(sc);          // pad slots: exp2(-1e30) = 0
                l += p;
                aw = fmaf(p, sc, aw);            // fma(0, -1e30, aw) = aw exactly
            }
        }
        l  += __shfl_xor(l, 16, 64); aw += __shfl_xor(aw, 16, 64);
        l  += __shfl_xor(l, 32, 64); aw += __shfl_xor(aw, 32, 64);
        if (quad == 0 && r < RR)
            out[(size_t)b * RR + r] = aw * __builtin_amdgcn_rcpf(l) * LN2;
    }
}

extern "C" void kernel_launch(void* const* d_in, const int* in_sizes, int n_in,
                              void* d_out, int out_size, void* d_ws, size_t ws_size,
                              hipStream_t stream) {
    const int*   poi_idx  = (const int*)d_in[0];
    const int*   hourw    = (const int*)d_in[1];
    const float* lat      = (const float*)d_in[2];
    const float* lon      = (const float*)d_in[3];
    const float* tmin     = (const float*)d_in[4];
    const float* cent     = (const float*)d_in[5];
    const float* poi_emb  = (const float*)d_in[6];
    const float* time_emb = (const float*)d_in[7];
    const float* E_t      = (const float*)d_in[8];
    const float* E_d      = (const float*)d_in[9];
    const float* E_dm     = (const float*)d_in[10];
    const float* Remb     = (const float*)d_in[11];
    const float* Wq       = (const float*)d_in[12];
    const float* Wk       = (const float*)d_in[13];
    const float* Wv       = (const float*)d_in[14];
    float* out            = (float*)d_out;

    unsigned short* Mtb = (unsigned short*)d_ws;            // 128*128 bf16 (32 KB)
    unsigned short* Gpb = Mtb + DD * DD;                    // 1024*128 bf16 (256 KB, frag order)

    prep_mg<<<dim3(DD + 1024), DD, 0, stream>>>(Wq, Wk, Wv, Remb, Mtb, Gpb);
    stan_fused<<<dim3(BB), 256, 0, stream>>>(poi_idx, hourw, lat, lon, tmin,
                                             poi_emb, time_emb, E_t, E_d, E_dm,
                                             Mtb, Gpb, cent, out);
}